// Round 7
// baseline (232.558 us; speedup 1.0000x reference)
//
#include <hip/hip_runtime.h>
#include <hip/hip_bf16.h>

#define N_NODES  100000
#define E_EDGES  50000
#define U_NODES  50000
#define D        128
#define NPE      32

typedef __attribute__((ext_vector_type(8))) short short8;       // 8 bf16 = 4 VGPR
typedef __attribute__((ext_vector_type(4))) unsigned short u16x4;
typedef __attribute__((ext_vector_type(4))) float f32x4;

// f32 -> bf16 bits, round-to-nearest-even (finite inputs only)
static __device__ __forceinline__ unsigned short f2bf_bits(float f) {
    unsigned u = __float_as_uint(f);
    return (unsigned short)((u + 0x7fffu + ((u >> 16) & 1u)) >> 16);
}

// ---------------------------------------------------------------------------
// Prep: Wt[which][c][k] = bf16(W[k][c])  (transposed so MFMA B-fragments are
// contiguous 8-elem k-runs).
// ---------------------------------------------------------------------------
__global__ void prep_wt(const float* __restrict__ w1, const float* __restrict__ w2,
                        unsigned short* __restrict__ wt) {
    const int t = blockIdx.x * 256 + threadIdx.x;   // 0..32767
    const int which = t >> 14;
    const int e = t & 16383;
    const int k = e >> 7, c = e & 127;
    const float* w = which ? w2 : w1;
    wt[which * 16384 + c * 128 + k] = f2bf_bits(w[e]);
}

// ---------------------------------------------------------------------------
// Convert x (f32) -> xb (bf16). 8 elems / thread, fully coalesced.
// ---------------------------------------------------------------------------
__global__ __launch_bounds__(256) void convert_x(const float* __restrict__ x,
                                                 unsigned short* __restrict__ xb,
                                                 int n8) {
    const int i = blockIdx.x * 256 + threadIdx.x;
    if (i >= n8) return;
    const float4 a = ((const float4*)x)[2 * i];
    const float4 b = ((const float4*)x)[2 * i + 1];
    uint4 o;
    o.x = (unsigned)f2bf_bits(a.x) | ((unsigned)f2bf_bits(a.y) << 16);
    o.y = (unsigned)f2bf_bits(a.z) | ((unsigned)f2bf_bits(a.w) << 16);
    o.z = (unsigned)f2bf_bits(b.x) | ((unsigned)f2bf_bits(b.y) << 16);
    o.w = (unsigned)f2bf_bits(b.z) | ((unsigned)f2bf_bits(b.w) << 16);
    ((uint4*)xb)[i] = o;
}

// ---------------------------------------------------------------------------
// Gather + masked mean over bf16 rows; one wave per output row.
// Lane group g = lane>>4 handles slots 4i+g; each lane loads 16B (8 bf16) ->
// one dwordx4 covers 4 rows; 8 instructions cover all 32 slots. The memory
// fence between load loop and FMA loop stops the compiler from sinking loads
// into the consumption loop (round-4 evidence: VGPR=28, ~2 loads in flight).
// Masked slots contribute via weight-0 FMA (id in [0,N): load always safe).
// Weights = 1/count over idx>0 slots (1/32 over all if count==0) == softmax
// over {1, -9e15} exactly.
// ---------------------------------------------------------------------------
template<int OUT_BF16, int RELU>
__global__ __launch_bounds__(256) void gather_mean4(
        const unsigned short* __restrict__ src, const int* __restrict__ idx,
        void* __restrict__ dst, int M) {
    const int wid = (int)((blockIdx.x * blockDim.x + threadIdx.x) >> 6);
    if (wid >= M) return;
    const int lane = threadIdx.x & 63;
    const int g = lane >> 4;     // row-slot group
    const int c = lane & 15;     // 16B chunk within row

    int my = 0;
    if (lane < NPE) my = idx[(size_t)wid * NPE + lane];
    const unsigned long long b = __ballot(lane < NPE && my > 0);
    const int count = __popcll(b);
    const float scale = 1.0f / (float)(count > 0 ? count : NPE);
    const bool take_all = (count == 0);

    uint4 v[8];
    float w[8];
#pragma unroll
    for (int i = 0; i < 8; ++i) {
        const int id = __shfl(my, i * 4 + g);
        w[i] = (take_all || id > 0) ? scale : 0.0f;
        v[i] = *(const uint4*)(src + (size_t)id * D + c * 8);
    }
    // scheduling fence: no memory op may cross -> all 8 loads issue first
    asm volatile("" ::: "memory");

    float acc[8] = {0.f, 0.f, 0.f, 0.f, 0.f, 0.f, 0.f, 0.f};
#pragma unroll
    for (int i = 0; i < 8; ++i) {
        acc[0] = fmaf(__uint_as_float(v[i].x << 16),         w[i], acc[0]);
        acc[1] = fmaf(__uint_as_float(v[i].x & 0xffff0000u), w[i], acc[1]);
        acc[2] = fmaf(__uint_as_float(v[i].y << 16),         w[i], acc[2]);
        acc[3] = fmaf(__uint_as_float(v[i].y & 0xffff0000u), w[i], acc[3]);
        acc[4] = fmaf(__uint_as_float(v[i].z << 16),         w[i], acc[4]);
        acc[5] = fmaf(__uint_as_float(v[i].z & 0xffff0000u), w[i], acc[5]);
        acc[6] = fmaf(__uint_as_float(v[i].w << 16),         w[i], acc[6]);
        acc[7] = fmaf(__uint_as_float(v[i].w & 0xffff0000u), w[i], acc[7]);
    }

    // reduce the 4 row-groups; every lane ends with full sums for its cols
#pragma unroll
    for (int i = 0; i < 8; ++i) {
        acc[i] += __shfl_xor(acc[i], 16);
        acc[i] += __shfl_xor(acc[i], 32);
        if (RELU) acc[i] = fmaxf(acc[i], 0.f);
    }

    if (lane < 16) {
        if (OUT_BF16) {
            uint4 o;
            o.x = (unsigned)f2bf_bits(acc[0]) | ((unsigned)f2bf_bits(acc[1]) << 16);
            o.y = (unsigned)f2bf_bits(acc[2]) | ((unsigned)f2bf_bits(acc[3]) << 16);
            o.z = (unsigned)f2bf_bits(acc[4]) | ((unsigned)f2bf_bits(acc[5]) << 16);
            o.w = (unsigned)f2bf_bits(acc[6]) | ((unsigned)f2bf_bits(acc[7]) << 16);
            *(uint4*)((unsigned short*)dst + (size_t)wid * D + c * 8) = o;
        } else {
            float* dp = (float*)dst + (size_t)wid * D + c * 8;
            *(float4*)dp = make_float4(acc[0], acc[1], acc[2], acc[3]);
            *(float4*)(dp + 4) = make_float4(acc[4], acc[5], acc[6], acc[7]);
        }
    }
}

// ---------------------------------------------------------------------------
// Fused double GEMM: e1[M,128] = bf16( relu(gx @ W1) @ W2 ), all bf16 MFMA.
// Uses the linearity refactor: gx = masked_mean(xb[seq]) so gx@W1 ==
// masked_mean(h[seq]).  Each wave owns rows 16wv..16wv+15 end-to-end:
// stage1 D-frags are relu'd, written to the wave's OWN 16 rows of sA, and
// re-read as stage2 A-frags (same-wave DS ordering, no extra barrier).
// Frag layouts (16x16x32): A: lane l, reg j -> A[l&15][32kt + 8(l>>4)+j]
//                          B: lane l, reg j -> W[32kt + 8(l>>4)+j][l&15]
//                          D: lane l, reg i -> D[4(l>>4)+i][l&15]
// ---------------------------------------------------------------------------
__global__ __launch_bounds__(256) void gemm12(const unsigned short* __restrict__ gx,
                                              const unsigned short* __restrict__ Wt,
                                              unsigned short* __restrict__ e1, int M) {
    __shared__ unsigned short sW1[128 * 136];  // 34.8 KB
    __shared__ unsigned short sW2[128 * 136];  // 34.8 KB
    __shared__ unsigned short sA[64 * 136];    // 17.4 KB (gx tile -> t -> out bounce)
    const int tid = threadIdx.x;

    // stage both transposed weights once per block
    {
        const float4* w4 = (const float4*)Wt;
#pragma unroll
        for (int j = 0; j < 8; ++j) {
            const int i = tid + j * 256;            // 2048 float4
            const int r = i >> 4, c16 = i & 15;
            *(float4*)&sW1[r * 136 + c16 * 8] = w4[i];
            *(float4*)&sW2[r * 136 + c16 * 8] = w4[2048 + i];
        }
    }

    const int ntiles = (M + 63) >> 6;
    const int lane = tid & 63;
    const int wv = tid >> 6;
    const int r16 = lane & 15;
    const int hi = lane >> 4;

    float4 pf[4];
    auto load_tile = [&](int tile) {
        const int row0 = tile << 6;
#pragma unroll
        for (int j = 0; j < 4; ++j) {
            const int i = tid + j * 256;            // 1024 x 16B (8 bf16)
            int gr = row0 + (i >> 4); if (gr >= M) gr = M - 1;
            pf[j] = *(const float4*)&gx[(size_t)gr * D + (i & 15) * 8];
        }
    };

    int tile = blockIdx.x;
    if (tile >= ntiles) return;
    load_tile(tile);

    while (tile < ntiles) {
        // cooperative: pf -> sA (gx tile)
#pragma unroll
        for (int j = 0; j < 4; ++j) {
            const int i = tid + j * 256;
            *(float4*)&sA[(i >> 4) * 136 + (i & 15) * 8] = pf[j];
        }
        __syncthreads();

        const int next = tile + gridDim.x;
        if (next < ntiles) load_tile(next);         // overlap HBM latency
        asm volatile("" ::: "memory");              // don't sink prefetch loads

        // stage 1: t = relu(gx @ W1)
        short8 af[4];
#pragma unroll
        for (int kt = 0; kt < 4; ++kt)
            af[kt] = *(const short8*)&sA[(wv * 16 + r16) * 136 + kt * 32 + hi * 8];

        f32x4 acc[8];
#pragma unroll
        for (int ct = 0; ct < 8; ++ct) acc[ct] = (f32x4){0.f, 0.f, 0.f, 0.f};
#pragma unroll
        for (int ct = 0; ct < 8; ++ct)
#pragma unroll
            for (int kt = 0; kt < 4; ++kt) {
                const short8 bf = *(const short8*)&sW1[(ct * 16 + r16) * 136 + kt * 32 + hi * 8];
                acc[ct] = __builtin_amdgcn_mfma_f32_16x16x32_bf16(af[kt], bf, acc[ct], 0, 0, 0);
            }

        // relu + write t into this wave's OWN 16 rows (same-wave DS ordering)
#pragma unroll
        for (int ct = 0; ct < 8; ++ct)
#pragma unroll
            for (int i = 0; i < 4; ++i)
                sA[(wv * 16 + hi * 4 + i) * 136 + ct * 16 + r16] =
                    f2bf_bits(fmaxf(acc[ct][i], 0.f));

        // stage 2: e1 = t @ W2  (A-frags re-read from own rows)
        short8 af2[4];
#pragma unroll
        for (int kt = 0; kt < 4; ++kt)
            af2[kt] = *(const short8*)&sA[(wv * 16 + r16) * 136 + kt * 32 + hi * 8];

        f32x4 acc2[8];
#pragma unroll
        for (int ct = 0; ct < 8; ++ct) acc2[ct] = (f32x4){0.f, 0.f, 0.f, 0.f};
#pragma unroll
        for (int ct = 0; ct < 8; ++ct)
#pragma unroll
            for (int kt = 0; kt < 4; ++kt) {
                const short8 bf = *(const short8*)&sW2[(ct * 16 + r16) * 136 + kt * 32 + hi * 8];
                acc2[ct] = __builtin_amdgcn_mfma_f32_16x16x32_bf16(af2[kt], bf, acc2[ct], 0, 0, 0);
            }

        // write result into own rows as bf16 (reuse sA as bounce)
#pragma unroll
        for (int ct = 0; ct < 8; ++ct)
#pragma unroll
            for (int i = 0; i < 4; ++i)
                sA[(wv * 16 + hi * 4 + i) * 136 + ct * 16 + r16] = f2bf_bits(acc2[ct][i]);
        __syncthreads();

        // cooperative coalesced store
        const int row0 = tile << 6;
        const int nrows = min(64, M - row0);
#pragma unroll
        for (int j = 0; j < 4; ++j) {
            const int i = tid + j * 256;            // 1024 x 16B chunks
            const int r = i >> 4, cc = i & 15;
            if (r < nrows)
                *(float4*)&e1[(size_t)(row0 + r) * D + cc * 8] =
                    *(const float4*)&sA[r * 136 + cc * 8];
        }
        __syncthreads();                            // before next tile staging
        tile = next;
    }
}

extern "C" void kernel_launch(void* const* d_in, const int* in_sizes, int n_in,
                              void* d_out, int out_size, void* d_ws, size_t ws_size,
                              hipStream_t stream) {
    const float* x    = (const float*)d_in[0];   // [N,128] f32
    const int*   seq  = (const int*)d_in[1];     // [E,32]
    const int*   useq = (const int*)d_in[3];     // [U,32]
    const float* w1   = (const float*)d_in[5];   // [128,128] f32
    const float* w2   = (const float*)d_in[6];   // [128,128] f32
    float* out = (float*)d_out;                  // [U,128] f32

    // workspace: Wt 64KB | xb bf16 25.6MB | gx bf16 12.8MB | e1 bf16 12.8MB
    unsigned short* wt = (unsigned short*)d_ws;
    unsigned short* xb = wt + 2 * 16384;
    unsigned short* gx = xb + (size_t)N_NODES * D;
    unsigned short* e1 = gx + (size_t)E_EDGES * D;

    prep_wt<<<128, 256, 0, stream>>>(w1, w2, wt);
    convert_x<<<(N_NODES * D / 8 + 255) / 256, 256, 0, stream>>>(x, xb, N_NODES * D / 8);

    // 1) gx = bf16(masked_mean(xb[seq]))          [linearity: == mean(h[seq])/W1-swap]
    gather_mean4<1, 0><<<(E_EDGES * 64) / 256, 256, 0, stream>>>(xb, seq, gx, E_EDGES);

    // 2) e1 = bf16(relu(gx @ W1) @ W2)
    gemm12<<<512, 256, 0, stream>>>(gx, wt, e1, E_EDGES);

    // 3) out = masked_mean(e1[useq])  (f32 out)
    gather_mean4<0, 0><<<(U_NODES * 64) / 256, 256, 0, stream>>>(e1, useq, out, U_NODES);
}

// Round 8
// 216.950 us; speedup vs baseline: 1.0719x; 1.0719x over previous
//
#include <hip/hip_runtime.h>
#include <hip/hip_bf16.h>

#define N_NODES  100000
#define E_EDGES  50000
#define U_NODES  50000
#define D        128
#define NPE      32

typedef __attribute__((ext_vector_type(8))) short short8;       // 8 bf16 = 4 VGPR
typedef __attribute__((ext_vector_type(4))) unsigned short u16x4;
typedef __attribute__((ext_vector_type(4))) float f32x4;
typedef __attribute__((ext_vector_type(4))) unsigned int u32x4;

// f32 -> bf16 bits, round-to-nearest-even (finite inputs only)
static __device__ __forceinline__ unsigned short f2bf_bits(float f) {
    unsigned u = __float_as_uint(f);
    return (unsigned short)((u + 0x7fffu + ((u >> 16) & 1u)) >> 16);
}

// XOR-swizzled LDS byte offset for a [rows][128] bf16 tile with 256B rows:
// chunk (16B) index XOR'd with row&7 -> frag reads spread over 8 chunk slots
// (~2-way bank aliasing = free per m136). 16B-granular ops keep alignment.
static __device__ __forceinline__ int swz(int row, int bytecol) {
    return row * 256 + ((((bytecol >> 4) ^ (row & 7)) << 4) | (bytecol & 15));
}

// ---------------------------------------------------------------------------
// Prep: Wt[which][c][k] = bf16(W[k][c])  (transposed so MFMA B-fragments are
// contiguous 8-elem k-runs).
// ---------------------------------------------------------------------------
__global__ void prep_wt(const float* __restrict__ w1, const float* __restrict__ w2,
                        unsigned short* __restrict__ wt) {
    const int t = blockIdx.x * 256 + threadIdx.x;   // 0..32767
    const int which = t >> 14;
    const int e = t & 16383;
    const int k = e >> 7, c = e & 127;
    const float* w = which ? w2 : w1;
    wt[which * 16384 + c * 128 + k] = f2bf_bits(w[e]);
}

// ---------------------------------------------------------------------------
// Convert x (f32) -> xb (bf16). 8 elems / thread, fully coalesced.
// ---------------------------------------------------------------------------
__global__ __launch_bounds__(256) void convert_x(const float* __restrict__ x,
                                                 unsigned short* __restrict__ xb,
                                                 int n8) {
    const int i = blockIdx.x * 256 + threadIdx.x;
    if (i >= n8) return;
    const float4 a = ((const float4*)x)[2 * i];
    const float4 b = ((const float4*)x)[2 * i + 1];
    uint4 o;
    o.x = (unsigned)f2bf_bits(a.x) | ((unsigned)f2bf_bits(a.y) << 16);
    o.y = (unsigned)f2bf_bits(a.z) | ((unsigned)f2bf_bits(a.w) << 16);
    o.z = (unsigned)f2bf_bits(b.x) | ((unsigned)f2bf_bits(b.y) << 16);
    o.w = (unsigned)f2bf_bits(b.z) | ((unsigned)f2bf_bits(b.w) << 16);
    ((uint4*)xb)[i] = o;
}

// ---------------------------------------------------------------------------
// Gather + masked mean over bf16 rows; one wave per output row.
// Lane group g = lane>>4 handles slots 4i+g; lane loads 16B (8 bf16) of the
// row. The 8 row-loads are issued via INLINE ASM global_load_dwordx4: the
// compiler cannot see them as loads, so it cannot interleave per-load waits
// with consumption (round-4/7 evidence: compiler kept only ~2 in flight,
// VGPR=28/32). One explicit s_waitcnt vmcnt(0) + sched_barrier(0) fences all
// consumption after all 8 loads are in flight (rule 18).
// Masked slots contribute via weight-0 FMA (id in [0,N): load always safe).
// Weights = 1/count over idx>0 slots (1/32 over all if count==0) == softmax
// over {1, -9e15} exactly.
// ---------------------------------------------------------------------------
template<int OUT_BF16, int RELU>
__global__ __launch_bounds__(256) void gather_mean4(
        const unsigned short* __restrict__ src, const int* __restrict__ idx,
        void* __restrict__ dst, int M) {
    const int wid = (int)((blockIdx.x * blockDim.x + threadIdx.x) >> 6);
    if (wid >= M) return;
    const int lane = threadIdx.x & 63;
    const int g = lane >> 4;     // row-slot group
    const int c = lane & 15;     // 16B chunk within row

    int my = 0;
    if (lane < NPE) my = idx[(size_t)wid * NPE + lane];
    const unsigned long long b = __ballot(lane < NPE && my > 0);
    const int count = __popcll(b);
    const float scale = 1.0f / (float)(count > 0 ? count : NPE);
    const bool take_all = (count == 0);

    const unsigned short* base = src + c * 8;
    u32x4 v[8];
    float w[8];
#pragma unroll
    for (int i = 0; i < 8; ++i) {
        const int id = __shfl(my, i * 4 + g);
        w[i] = (take_all || id > 0) ? scale : 0.0f;
        const unsigned short* p = base + (size_t)id * D;
        asm volatile("global_load_dwordx4 %0, %1, off"
                     : "=v"(v[i]) : "v"(p));
    }
    asm volatile("s_waitcnt vmcnt(0)" ::: "memory");
    __builtin_amdgcn_sched_barrier(0);   // nothing crosses (rule 18)

    float acc[8] = {0.f, 0.f, 0.f, 0.f, 0.f, 0.f, 0.f, 0.f};
#pragma unroll
    for (int i = 0; i < 8; ++i) {
        acc[0] = fmaf(__uint_as_float(v[i].x << 16),         w[i], acc[0]);
        acc[1] = fmaf(__uint_as_float(v[i].x & 0xffff0000u), w[i], acc[1]);
        acc[2] = fmaf(__uint_as_float(v[i].y << 16),         w[i], acc[2]);
        acc[3] = fmaf(__uint_as_float(v[i].y & 0xffff0000u), w[i], acc[3]);
        acc[4] = fmaf(__uint_as_float(v[i].z << 16),         w[i], acc[4]);
        acc[5] = fmaf(__uint_as_float(v[i].z & 0xffff0000u), w[i], acc[5]);
        acc[6] = fmaf(__uint_as_float(v[i].w << 16),         w[i], acc[6]);
        acc[7] = fmaf(__uint_as_float(v[i].w & 0xffff0000u), w[i], acc[7]);
    }

    // reduce the 4 row-groups; every lane ends with full sums for its cols
#pragma unroll
    for (int i = 0; i < 8; ++i) {
        acc[i] += __shfl_xor(acc[i], 16);
        acc[i] += __shfl_xor(acc[i], 32);
        if (RELU) acc[i] = fmaxf(acc[i], 0.f);
    }

    if (lane < 16) {
        if (OUT_BF16) {
            uint4 o;
            o.x = (unsigned)f2bf_bits(acc[0]) | ((unsigned)f2bf_bits(acc[1]) << 16);
            o.y = (unsigned)f2bf_bits(acc[2]) | ((unsigned)f2bf_bits(acc[3]) << 16);
            o.z = (unsigned)f2bf_bits(acc[4]) | ((unsigned)f2bf_bits(acc[5]) << 16);
            o.w = (unsigned)f2bf_bits(acc[6]) | ((unsigned)f2bf_bits(acc[7]) << 16);
            *(uint4*)((unsigned short*)dst + (size_t)wid * D + c * 8) = o;
        } else {
            float* dp = (float*)dst + (size_t)wid * D + c * 8;
            *(float4*)dp = make_float4(acc[0], acc[1], acc[2], acc[3]);
            *(float4*)(dp + 4) = make_float4(acc[4], acc[5], acc[6], acc[7]);
        }
    }
}

// ---------------------------------------------------------------------------
// Fused double GEMM, one-shot: e1[M,128] = bf16( relu(gx @ W1) @ W2 ).
// 1024-thread blocks (16 waves), 256 rows per block, grid = ceil(M/256) =
// one pass: weights staged ONCE per 256 rows of work (round-7 fix: 87KB LDS
// gave 1 blk/CU x 4 waves = 1 wave/SIMD; now 16 waves/CU = 4/SIMD).
// LDS unpadded + XOR-swizzled (swz) -> 128KB total, ~2-way conflicts.
// Wave wv owns rows 16wv..16wv+15 end-to-end: stage1 D-frags relu'd into its
// OWN rows of sA, re-read as stage2 A-frags (same-wave DS ordering; this
// bounce pattern HW-validated in rounds 5/7, absmax 4.9e-4).
// Frag layouts (16x16x32): A: lane l, reg j -> A[l&15][32kt + 8(l>>4)+j]
//                          B: lane l, reg j -> W[32kt + 8(l>>4)+j][l&15]
//                          D: lane l, reg i -> D[4(l>>4)+i][l&15]
// ---------------------------------------------------------------------------
__global__ __launch_bounds__(1024) void gemm12(const unsigned short* __restrict__ gx,
                                               const unsigned short* __restrict__ Wt,
                                               unsigned short* __restrict__ e1, int M) {
    __shared__ unsigned short sW1[128 * 128];  // 32 KB (swizzled)
    __shared__ unsigned short sW2[128 * 128];  // 32 KB (swizzled)
    __shared__ unsigned short sA[256 * 128];   // 64 KB (swizzled; gx->t->out)
    const int tid = threadIdx.x;
    const int row0 = blockIdx.x * 256;
    const int nrows = min(256, M - row0);

    // stage both transposed weights (2048 float4 each; 2 per thread each)
    {
        const float4* w4 = (const float4*)Wt;
#pragma unroll
        for (int j = 0; j < 2; ++j) {
            const int i = tid + j * 1024;           // 0..2047
            const int r = i >> 4, cc = (i & 15) * 16;
            *(float4*)((char*)sW1 + swz(r, cc)) = w4[i];
            *(float4*)((char*)sW2 + swz(r, cc)) = w4[2048 + i];
        }
    }
    // stage gx tile (4096 chunks of 16B; 4 per thread), row-clamped at tail
    {
#pragma unroll
        for (int j = 0; j < 4; ++j) {
            const int i = tid + j * 1024;           // 0..4095
            const int r = i >> 4, cc = (i & 15) * 16;
            int gr = row0 + r; if (gr >= M) gr = M - 1;
            *(float4*)((char*)sA + swz(r, cc)) =
                *(const float4*)&gx[(size_t)gr * D + (i & 15) * 8];
        }
    }
    __syncthreads();

    const int lane = tid & 63;
    const int wv = tid >> 6;        // 0..15
    const int r16 = lane & 15;
    const int hi = lane >> 4;
    const int Ra = wv * 16 + r16;   // this lane's A-frag row

    // stage 1: t = relu(gx @ W1)
    short8 af[4];
#pragma unroll
    for (int kt = 0; kt < 4; ++kt)
        af[kt] = *(const short8*)((char*)sA + swz(Ra, kt * 64 + hi * 16));

    f32x4 acc[8];
#pragma unroll
    for (int ct = 0; ct < 8; ++ct) acc[ct] = (f32x4){0.f, 0.f, 0.f, 0.f};
#pragma unroll
    for (int ct = 0; ct < 8; ++ct)
#pragma unroll
        for (int kt = 0; kt < 4; ++kt) {
            const short8 bf = *(const short8*)((char*)sW1 + swz(ct * 16 + r16, kt * 64 + hi * 16));
            acc[ct] = __builtin_amdgcn_mfma_f32_16x16x32_bf16(af[kt], bf, acc[ct], 0, 0, 0);
        }

    // relu + write t into this wave's OWN 16 rows (same-wave DS ordering)
#pragma unroll
    for (int ct = 0; ct < 8; ++ct)
#pragma unroll
        for (int i = 0; i < 4; ++i)
            *(unsigned short*)((char*)sA + swz(wv * 16 + hi * 4 + i, (ct * 16 + r16) * 2)) =
                f2bf_bits(fmaxf(acc[ct][i], 0.f));

    // stage 2: e1 = t @ W2  (A-frags re-read from own rows)
    short8 af2[4];
#pragma unroll
    for (int kt = 0; kt < 4; ++kt)
        af2[kt] = *(const short8*)((char*)sA + swz(Ra, kt * 64 + hi * 16));

    f32x4 acc2[8];
#pragma unroll
    for (int ct = 0; ct < 8; ++ct) acc2[ct] = (f32x4){0.f, 0.f, 0.f, 0.f};
#pragma unroll
    for (int ct = 0; ct < 8; ++ct)
#pragma unroll
        for (int kt = 0; kt < 4; ++kt) {
            const short8 bf = *(const short8*)((char*)sW2 + swz(ct * 16 + r16, kt * 64 + hi * 16));
            acc2[ct] = __builtin_amdgcn_mfma_f32_16x16x32_bf16(af2[kt], bf, acc2[ct], 0, 0, 0);
        }

    // write result into own rows as bf16 (sA as bounce)
#pragma unroll
    for (int ct = 0; ct < 8; ++ct)
#pragma unroll
        for (int i = 0; i < 4; ++i)
            *(unsigned short*)((char*)sA + swz(wv * 16 + hi * 4 + i, (ct * 16 + r16) * 2)) =
                f2bf_bits(acc2[ct][i]);
    __syncthreads();

    // cooperative coalesced store
#pragma unroll
    for (int j = 0; j < 4; ++j) {
        const int i = tid + j * 1024;               // 0..4095 16B chunks
        const int r = i >> 4, cc = i & 15;
        if (r < nrows)
            *(float4*)&e1[(size_t)(row0 + r) * D + cc * 8] =
                *(const float4*)((char*)sA + swz(r, cc * 16));
    }
}

extern "C" void kernel_launch(void* const* d_in, const int* in_sizes, int n_in,
                              void* d_out, int out_size, void* d_ws, size_t ws_size,
                              hipStream_t stream) {
    const float* x    = (const float*)d_in[0];   // [N,128] f32
    const int*   seq  = (const int*)d_in[1];     // [E,32]
    const int*   useq = (const int*)d_in[3];     // [U,32]
    const float* w1   = (const float*)d_in[5];   // [128,128] f32
    const float* w2   = (const float*)d_in[6];   // [128,128] f32
    float* out = (float*)d_out;                  // [U,128] f32

    // workspace: Wt 64KB | xb bf16 25.6MB | gx bf16 12.8MB | e1 bf16 12.8MB
    unsigned short* wt = (unsigned short*)d_ws;
    unsigned short* xb = wt + 2 * 16384;
    unsigned short* gx = xb + (size_t)N_NODES * D;
    unsigned short* e1 = gx + (size_t)E_EDGES * D;

    prep_wt<<<128, 256, 0, stream>>>(w1, w2, wt);
    convert_x<<<(N_NODES * D / 8 + 255) / 256, 256, 0, stream>>>(x, xb, N_NODES * D / 8);

    // 1) gx = bf16(masked_mean(xb[seq]))          [linearity: == mean(h[seq])]
    gather_mean4<1, 0><<<(E_EDGES * 64) / 256, 256, 0, stream>>>(xb, seq, gx, E_EDGES);

    // 2) e1 = bf16(relu(gx @ W1) @ W2)  — one-shot, 256 rows/block
    gemm12<<<(E_EDGES + 255) / 256, 1024, 0, stream>>>(gx, wt, e1, E_EDGES);

    // 3) out = masked_mean(e1[useq])  (f32 out)
    gather_mean4<0, 0><<<(U_NODES * 64) / 256, 256, 0, stream>>>(e1, useq, out, U_NODES);
}